// Round 7
// baseline (132.633 us; speedup 1.0000x reference)
//
#include <hip/hip_runtime.h>
#include <hip/hip_bf16.h>

// SubnetGate = gathered grouped GEMM (B=16384, K=512, N=512, E=8, col 0).
// R7: barrier-free fragment-direct GEMM. Both operands pre-stored in exact
// MFMA fragment order; each lane global_load_dwordx4's its fragments
// (lane-consecutive 16B => perfectly coalesced). No LDS, no __syncthreads in
// the k-loop => no vmcnt(0) drains; compiler pipelines with fine vmcnt.
//
// ws layout:
//   [0,32)      int counts[8]
//   [64,68)     int ndesc
//   [128,1184)  int desc[264]            (e<<16 | mt), BM=64 tiles
//   [4096,528384)      int rowlist[8][16384]
//   [528384,4722688)   ushort Wf[8][8 kt][2 kf][32 nf][64 lane][8]   (4MB)
//   [4722688,22024192) ushort xf[264 d][8 kt][2 kf][4 mf][64 lane][8] (17MB)
//
// Fragment semantics (verified R0-R6, absmax 0.031):
//   A/B frag: lane ln=(q*16+l15) holds op[row=l15][k = q*8+j], j=0..7
//   C/D:      col = l15, row = q*4 + r

#define NROWS   16384
#define KDIM    512
#define NDIM    512
#define NEXP    8
#define MAX_DESC 264
#define WS_NDESC_OFF   64
#define WS_DESC_OFF    128
#define WS_ROWLIST_OFF 4096
#define WS_WT_OFF      (4096 + NEXP * NROWS * 4)
#define WS_XG_OFF      (WS_WT_OFF + NEXP * KDIM * NDIM * 2)
#define WS_NEED        ((size_t)WS_XG_OFF + (size_t)MAX_DESC * 8 * 4096 * 2)

typedef __bf16        bf16x8 __attribute__((ext_vector_type(8)));
typedef float         f32x4  __attribute__((ext_vector_type(4)));
typedef unsigned int  u32x4  __attribute__((ext_vector_type(4)));

__device__ __forceinline__ unsigned int f2bf_u(float f) {
    unsigned int u = __builtin_bit_cast(unsigned int, f);
    return (u + 0x7FFFu + ((u >> 16) & 1u)) >> 16;   // RNE f32->bf16
}
__device__ __forceinline__ unsigned int pack2(float a, float b) {
    return f2bf_u(a) | (f2bf_u(b) << 16);
}
__device__ __forceinline__ u32x4 pack8(f32x4 a, f32x4 b) {
    u32x4 p;
    p.x = pack2(a.x, a.y); p.y = pack2(a.z, a.w);
    p.z = pack2(b.x, b.y); p.w = pack2(b.z, b.w);
    return p;
}

__global__ void zero_kernel(int* __restrict__ gcnt) {
    if (threadIdx.x < NEXP) gcnt[threadIdx.x] = 0;
}

// 64 blocks: histogram+scatter 256 rows each into per-expert rowlists.
__global__ void hist_kernel(const int* __restrict__ groups,
                            int* __restrict__ gcnt,
                            int* __restrict__ rowlist) {
    __shared__ int lcnt[NEXP];
    __shared__ int lbase[NEXP];
    const int tid = threadIdx.x;
    const int base = blockIdx.x * 256;
    if (tid < NEXP) lcnt[tid] = 0;
    __syncthreads();
    int r = base + tid;
    int e = groups[r * 2];               // group_col = 0
    int pos = atomicAdd(&lcnt[e], 1);
    __syncthreads();
    if (tid < NEXP) lbase[tid] = atomicAdd(&gcnt[tid], lcnt[tid]);
    __syncthreads();
    rowlist[e * NROWS + lbase[e] + pos] = r;
}

// desc[d] = (e<<16 | mt) for BM=64 m-tiles; ndesc = total descs.
__global__ void plan_kernel(const int* __restrict__ counts,
                            int* __restrict__ ndesc,
                            int* __restrict__ desc) {
    if (threadIdx.x == 0) {
        int M = 0;
        for (int e = 0; e < NEXP; ++e) {
            int nmt = (counts[e] + 63) >> 6;
            for (int mt = 0; mt < nmt && M < MAX_DESC; ++mt)
                desc[M++] = (e << 16) | mt;
        }
        ndesc[0] = M;
    }
}

// Fused staging kernel.
// blocks [0,64): prep_b (e=bid>>3, kt=bid&7): frag-permute W -> Wf.
//   granule gidx=kf*2048+nf*64+lane: n=nf*16+l15, k=kt*64+kf*32+q*8+j.
//   reads: 16-lane groups hit 64B-contiguous W rows; writes contiguous 16B.
// blocks [64,...): gather (d=(bid-64)>>3, kt=(bid-64)&7): gather+cast x -> xf.
//   granule gidx=kf*256+mf*64+lane: m=mf*16+l15, k=kt*64+kf*32+q*8+j.
__global__ __launch_bounds__(256, 4)
void stage_kernel(const float* __restrict__ x,
                  const float* __restrict__ W,
                  const int* __restrict__ counts,
                  const int* __restrict__ rowlist,
                  const int* __restrict__ ndesc,
                  const int* __restrict__ desc,
                  unsigned short* __restrict__ Wf,
                  unsigned short* __restrict__ xf) {
    const int bid = blockIdx.x;
    const int tid = threadIdx.x;

    if (bid < 64) {
        const int e  = bid >> 3;
        const int kt = bid & 7;
        const float* Wb = W + (size_t)e * (KDIM * NDIM);
        unsigned short* dst = Wf + ((size_t)(e * 8 + kt)) * 32768;  // shorts
        #pragma unroll
        for (int it = 0; it < 16; ++it) {
            int gidx = it * 256 + tid;           // 0..4095
            int lane = gidx & 63;
            int nf   = (gidx >> 6) & 31;
            int kf   = gidx >> 11;
            int q    = lane >> 4;
            int l15  = lane & 15;
            int n    = nf * 16 + l15;
            int k0   = kt * 64 + kf * 32 + q * 8;
            unsigned int p[4];
            #pragma unroll
            for (int jj = 0; jj < 4; ++jj)
                p[jj] = pack2(Wb[(size_t)(k0 + 2 * jj) * NDIM + n],
                              Wb[(size_t)(k0 + 2 * jj + 1) * NDIM + n]);
            *(u32x4*)&dst[(size_t)gidx * 8] = *(const u32x4*)p;
        }
    } else {
        const int b2 = bid - 64;
        const int d  = b2 >> 3;
        const int kt = b2 & 7;
        if (d >= ndesc[0]) return;
        const int de = desc[d];
        const int e  = de >> 16;
        const int mt = de & 0xffff;
        int m_valid = counts[e] - mt * 64;
        if (m_valid > 64) m_valid = 64;
        const int* rl = rowlist + e * NROWS + mt * 64;
        unsigned short* dst = xf + ((size_t)(d * 8 + kt)) * 4096;   // shorts
        #pragma unroll
        for (int it = 0; it < 2; ++it) {
            int gidx = it * 256 + tid;           // 0..511
            int lane = gidx & 63;
            int mf   = (gidx >> 6) & 3;
            int kf   = gidx >> 8;
            int q    = lane >> 4;
            int l15  = lane & 15;
            int m    = mf * 16 + l15;
            u32x4 p = {0u, 0u, 0u, 0u};
            if (m < m_valid) {
                const float* s = x + (size_t)rl[m] * KDIM + kt * 64 + kf * 32 + q * 8;
                p = pack8(*(const f32x4*)s, *(const f32x4*)(s + 4));
            }
            *(u32x4*)&dst[(size_t)gidx * 8] = p;
        }
    }
}

// Barrier-free fragment-direct GEMM. Wave-tile: 32 rows (half) x 64 cols
// (strip). Twaves = ndesc*16 (2 halves x 8 strips). Per k-step (kt,kf):
// 2 A-frag + 4 B-frag coalesced 16B/lane global loads + 8 MFMA; depth-2
// software pipeline; zero LDS, zero barriers.
__global__ __launch_bounds__(256, 3)
void gemm_frag(const unsigned short* __restrict__ xf,
               const int* __restrict__ counts,
               const int* __restrict__ rowlist,
               const unsigned short* __restrict__ Wf,
               const float* __restrict__ bias,
               float* __restrict__ out,
               const int* __restrict__ ndesc,
               const int* __restrict__ desc) {
    const int tid = threadIdx.x;
    const int w   = tid >> 6;
    const int ln  = tid & 63;
    const int q   = ln >> 4;
    const int l15 = ln & 15;

    const int Twaves = ndesc[0] * 16;
    for (int wt = blockIdx.x * 4 + w; wt < Twaves; wt += gridDim.x * 4) {
        const int d     = wt >> 4;
        const int half  = (wt >> 3) & 1;
        const int strip = wt & 7;
        const int de = desc[d];
        const int e  = de >> 16;
        const int mt = de & 0xffff;
        int m_valid = counts[e] - mt * 64;
        if (m_valid > 64) m_valid = 64;
        const int* rl = rowlist + e * NROWS + mt * 64;

        // shorts: xf frag base for (kt,kf,mf): d*32768 + kt*4096 + kf*2048 + mf*512 + ln*8
        const unsigned short* ab = xf + (size_t)d * 32768 + (half * 2) * 512 + ln * 8;
        // shorts: Wf frag base for (kt,kf,nf): e*262144 + kt*32768 + kf*16384 + nf*512 + ln*8
        const unsigned short* bb = Wf + (size_t)e * 262144 + (strip * 4) * 512 + ln * 8;

        f32x4 acc[2][4];
        #pragma unroll
        for (int mi = 0; mi < 2; ++mi)
            #pragma unroll
            for (int ni = 0; ni < 4; ++ni)
                acc[mi][ni] = (f32x4){0.f, 0.f, 0.f, 0.f};

        bf16x8 af[2][2], bv[2][4];
        // prologue: step 0 (kt=0, kf=0)
        #pragma unroll
        for (int mi = 0; mi < 2; ++mi)
            af[0][mi] = *(const bf16x8*)(ab + mi * 512);
        #pragma unroll
        for (int ni = 0; ni < 4; ++ni)
            bv[0][ni] = *(const bf16x8*)(bb + ni * 512);

        #pragma unroll
        for (int s = 0; s < 16; ++s) {
            const int buf = s & 1;
            if (s < 15) {
                const int s1 = s + 1;
                const int kt = s1 >> 1, kf = s1 & 1;
                const unsigned short* a1 = ab + kt * 4096 + kf * 2048;
                const unsigned short* b1 = bb + kt * 32768 + kf * 16384;
                #pragma unroll
                for (int mi = 0; mi < 2; ++mi)
                    af[buf ^ 1][mi] = *(const bf16x8*)(a1 + mi * 512);
                #pragma unroll
                for (int ni = 0; ni < 4; ++ni)
                    bv[buf ^ 1][ni] = *(const bf16x8*)(b1 + ni * 512);
            }
            #pragma unroll
            for (int mi = 0; mi < 2; ++mi)
                #pragma unroll
                for (int ni = 0; ni < 4; ++ni)
                    acc[mi][ni] = __builtin_amdgcn_mfma_f32_16x16x32_bf16(
                        af[buf][mi], bv[buf][ni], acc[mi][ni], 0, 0, 0);
        }

        // epilogue: +bias, masked scatter (C/D: col=l15, row=q*4+r)
        int growv[8];
        #pragma unroll
        for (int mi = 0; mi < 2; ++mi)
            #pragma unroll
            for (int r = 0; r < 4; ++r) {
                int rloc = half * 32 + mi * 16 + q * 4 + r;
                growv[mi * 4 + r] = (rloc < m_valid) ? rl[rloc] : -1;
            }
        #pragma unroll
        for (int ni = 0; ni < 4; ++ni) {
            int col = strip * 64 + ni * 16 + l15;
            float bvs = bias[e * NDIM + col];
            #pragma unroll
            for (int mi = 0; mi < 2; ++mi)
                #pragma unroll
                for (int r = 0; r < 4; ++r) {
                    int gr = growv[mi * 4 + r];
                    if (gr >= 0) out[(size_t)gr * NDIM + col] = acc[mi][ni][r] + bvs;
                }
        }
    }
}

extern "C" void kernel_launch(void* const* d_in, const int* in_sizes, int n_in,
                              void* d_out, int out_size, void* d_ws, size_t ws_size,
                              hipStream_t stream) {
    const float* x      = (const float*)d_in[0];   // (16384, 512) f32
    const int*   groups = (const int*)d_in[1];     // (16384, 2) i32
    const float* W      = (const float*)d_in[2];   // (8, 512, 512) f32
    const float* b      = (const float*)d_in[3];   // (8, 512) f32
    float*       out    = (float*)d_out;           // (16384, 512) f32

    char* ws = (char*)d_ws;
    int*            counts  = (int*)ws;
    int*            ndesc   = (int*)(ws + WS_NDESC_OFF);
    int*            desc    = (int*)(ws + WS_DESC_OFF);
    int*            rowlist = (int*)(ws + WS_ROWLIST_OFF);
    unsigned short* Wf      = (unsigned short*)(ws + WS_WT_OFF);
    unsigned short* xf      = (unsigned short*)(ws + WS_XG_OFF);

    zero_kernel<<<1, 64, 0, stream>>>(counts);
    hist_kernel<<<64, 256, 0, stream>>>(groups, counts, rowlist);
    plan_kernel<<<1, 64, 0, stream>>>(counts, ndesc, desc);
    stage_kernel<<<64 + MAX_DESC * 8, 256, 0, stream>>>(x, W, counts, rowlist,
                                                        ndesc, desc, Wf, xf);
    gemm_frag<<<1056, 256, 0, stream>>>(xf, counts, rowlist, Wf, b, out,
                                        ndesc, desc);
}

// Round 8
// 131.681 us; speedup vs baseline: 1.0072x; 1.0072x over previous
//
#include <hip/hip_runtime.h>
#include <hip/hip_bf16.h>

// SubnetGate = gathered grouped GEMM (B=16384, K=512, N=512, E=8, col 0).
// R8: barrier-free fragment-direct GEMM, 64x64 wave-tiles, depth-3 register
// pipeline, block = {4 consecutive d} x {one 64-col strip} (B loads identical
// across the block's 4 waves -> L1 dedup), XCD-sliced d-ranges (blockIdx%8)
// so each XCD's working set (~1.5MB) stays L2-resident.
//
// ws layout:
//   [0,32)      int counts[8]
//   [64,68)     int ndesc
//   [128,1184)  int desc[264]            (e<<16 | mt), BM=64 tiles
//   [4096,528384)      int rowlist[8][16384]
//   [528384,4722688)   ushort Wf[8][8 kt][2 kf][32 nf][64 lane][8]   (4MB)
//   [4722688,22024192) ushort xf[264 d][8 kt][2 kf][4 mf][64 lane][8] (17MB)
//
// Fragment semantics (verified R0-R7, absmax 0.031):
//   A/B frag: lane ln=(q*16+l15) holds op[row=l15][k = q*8+j], j=0..7
//   C/D:      col = l15, row = q*4 + r

#define NROWS   16384
#define KDIM    512
#define NDIM    512
#define NEXP    8
#define MAX_DESC 264
#define WS_NDESC_OFF   64
#define WS_DESC_OFF    128
#define WS_ROWLIST_OFF 4096
#define WS_WT_OFF      (4096 + NEXP * NROWS * 4)
#define WS_XG_OFF      (WS_WT_OFF + NEXP * KDIM * NDIM * 2)

typedef __bf16        bf16x8 __attribute__((ext_vector_type(8)));
typedef float         f32x4  __attribute__((ext_vector_type(4)));
typedef unsigned int  u32x4  __attribute__((ext_vector_type(4)));

__device__ __forceinline__ unsigned int f2bf_u(float f) {
    unsigned int u = __builtin_bit_cast(unsigned int, f);
    return (u + 0x7FFFu + ((u >> 16) & 1u)) >> 16;   // RNE f32->bf16
}
__device__ __forceinline__ unsigned int pack2(float a, float b) {
    return f2bf_u(a) | (f2bf_u(b) << 16);
}
__device__ __forceinline__ u32x4 pack8(f32x4 a, f32x4 b) {
    u32x4 p;
    p.x = pack2(a.x, a.y); p.y = pack2(a.z, a.w);
    p.z = pack2(b.x, b.y); p.w = pack2(b.z, b.w);
    return p;
}

// 64 blocks: histogram+scatter 256 rows each into per-expert rowlists.
__global__ void hist_kernel(const int* __restrict__ groups,
                            int* __restrict__ gcnt,
                            int* __restrict__ rowlist) {
    __shared__ int lcnt[NEXP];
    __shared__ int lbase[NEXP];
    const int tid = threadIdx.x;
    const int base = blockIdx.x * 256;
    if (tid < NEXP) lcnt[tid] = 0;
    __syncthreads();
    int r = base + tid;
    int e = groups[r * 2];               // group_col = 0
    int pos = atomicAdd(&lcnt[e], 1);
    __syncthreads();
    if (tid < NEXP) lbase[tid] = atomicAdd(&gcnt[tid], lcnt[tid]);
    __syncthreads();
    rowlist[e * NROWS + lbase[e] + pos] = r;
}

// desc[d] = (e<<16 | mt) for BM=64 m-tiles; ndesc = total descs.
__global__ void plan_kernel(const int* __restrict__ counts,
                            int* __restrict__ ndesc,
                            int* __restrict__ desc) {
    if (threadIdx.x == 0) {
        int M = 0;
        for (int e = 0; e < NEXP; ++e) {
            int nmt = (counts[e] + 63) >> 6;
            for (int mt = 0; mt < nmt && M < MAX_DESC; ++mt)
                desc[M++] = (e << 16) | mt;
        }
        ndesc[0] = M;
    }
}

// Fused staging kernel (verified R7).
// blocks [0,64): frag-permute W -> Wf for (e=bid>>3, kt=bid&7).
// blocks [64,...): gather+cast x -> xf for (d=(bid-64)>>3, kt=(bid-64)&7).
__global__ __launch_bounds__(256, 4)
void stage_kernel(const float* __restrict__ x,
                  const float* __restrict__ W,
                  const int* __restrict__ counts,
                  const int* __restrict__ rowlist,
                  const int* __restrict__ ndesc,
                  const int* __restrict__ desc,
                  unsigned short* __restrict__ Wf,
                  unsigned short* __restrict__ xf) {
    const int bid = blockIdx.x;
    const int tid = threadIdx.x;

    if (bid < 64) {
        const int e  = bid >> 3;
        const int kt = bid & 7;
        const float* Wb = W + (size_t)e * (KDIM * NDIM);
        unsigned short* dst = Wf + ((size_t)(e * 8 + kt)) * 32768;  // shorts
        #pragma unroll
        for (int it = 0; it < 16; ++it) {
            int gidx = it * 256 + tid;           // 0..4095
            int lane = gidx & 63;
            int nf   = (gidx >> 6) & 31;
            int kf   = gidx >> 11;
            int q    = lane >> 4;
            int l15  = lane & 15;
            int n    = nf * 16 + l15;
            int k0   = kt * 64 + kf * 32 + q * 8;
            unsigned int p[4];
            #pragma unroll
            for (int jj = 0; jj < 4; ++jj)
                p[jj] = pack2(Wb[(size_t)(k0 + 2 * jj) * NDIM + n],
                              Wb[(size_t)(k0 + 2 * jj + 1) * NDIM + n]);
            *(u32x4*)&dst[(size_t)gidx * 8] = *(const u32x4*)p;
        }
    } else {
        const int b2 = bid - 64;
        const int d  = b2 >> 3;
        const int kt = b2 & 7;
        if (d >= ndesc[0]) return;
        const int de = desc[d];
        const int e  = de >> 16;
        const int mt = de & 0xffff;
        int m_valid = counts[e] - mt * 64;
        if (m_valid > 64) m_valid = 64;
        const int* rl = rowlist + e * NROWS + mt * 64;
        unsigned short* dst = xf + ((size_t)(d * 8 + kt)) * 4096;   // shorts
        #pragma unroll
        for (int it = 0; it < 2; ++it) {
            int gidx = it * 256 + tid;           // 0..511
            int lane = gidx & 63;
            int mf   = (gidx >> 6) & 3;
            int kf   = gidx >> 8;
            int q    = lane >> 4;
            int l15  = lane & 15;
            int m    = mf * 16 + l15;
            u32x4 p = {0u, 0u, 0u, 0u};
            if (m < m_valid) {
                const float* s = x + (size_t)rl[m] * KDIM + kt * 64 + kf * 32 + q * 8;
                p = pack8(*(const f32x4*)s, *(const f32x4*)(s + 4));
            }
            *(u32x4*)&dst[(size_t)gidx * 8] = p;
        }
    }
}

// Barrier-free fragment-direct GEMM.
// Wave-tile: full 64 rows x 64-col strip. Block b: XCD j=b&7, i=b>>3 (0..71),
// strip=i/9, gl=i%9; group g=j*Gj+gl (Gj=ceil(nd4/8)); wave w handles
// d = g*4+w. The block's 4 waves share identical B fragments (L1 dedup).
// Per k-step: 4 A-frag + 4 B-frag 16B/lane coalesced loads + 16 MFMA;
// depth-3 register pipeline, fully unrolled; zero LDS, zero barriers.
__global__ __launch_bounds__(256, 2)
void gemm_frag(const unsigned short* __restrict__ xf,
               const int* __restrict__ counts,
               const int* __restrict__ rowlist,
               const unsigned short* __restrict__ Wf,
               const float* __restrict__ bias,
               float* __restrict__ out,
               const int* __restrict__ ndesc,
               const int* __restrict__ desc) {
    const int tid = threadIdx.x;
    const int w   = tid >> 6;
    const int ln  = tid & 63;
    const int q   = ln >> 4;
    const int l15 = ln & 15;

    const int nd  = ndesc[0];
    const int nd4 = (nd + 3) >> 2;
    const int Gj  = (nd4 + 7) >> 3;

    const int j     = blockIdx.x & 7;    // XCD slice
    const int i     = blockIdx.x >> 3;   // 0..71
    const int strip = i / 9;             // 0..7
    const int gl    = i - strip * 9;     // 0..8
    if (gl >= Gj) return;
    const int g = j * Gj + gl;
    if (g >= nd4) return;
    const int d = g * 4 + w;
    if (d >= nd) return;

    const int de = desc[d];
    const int e  = de >> 16;
    const int mt = de & 0xffff;
    int m_valid = counts[e] - mt * 64;
    if (m_valid > 64) m_valid = 64;
    const int* rl = rowlist + e * NROWS + mt * 64;

    // shorts: xf frag (kt,kf,mf) at d*32768 + kt*4096 + kf*2048 + mf*512 + ln*8
    const unsigned short* ab = xf + (size_t)d * 32768 + ln * 8;
    // shorts: Wf frag (kt,kf,nf) at e*262144 + kt*32768 + kf*16384 + nf*512 + ln*8
    const unsigned short* bb = Wf + (size_t)e * 262144 + strip * 4 * 512 + ln * 8;

    f32x4 acc[4][4];
    #pragma unroll
    for (int mi = 0; mi < 4; ++mi)
        #pragma unroll
        for (int ni = 0; ni < 4; ++ni)
            acc[mi][ni] = (f32x4){0.f, 0.f, 0.f, 0.f};

    bf16x8 af[3][4], bv[3][4];
    // prologue: steps 0,1 into slots 0,1  (step s: kt=s>>1, kf=s&1)
    #pragma unroll
    for (int s = 0; s < 2; ++s) {
        const int ao = (s >> 1) * 4096 + (s & 1) * 2048;
        const int bo = (s >> 1) * 32768 + (s & 1) * 16384;
        #pragma unroll
        for (int mi = 0; mi < 4; ++mi)
            af[s][mi] = *(const bf16x8*)(ab + ao + mi * 512);
        #pragma unroll
        for (int ni = 0; ni < 4; ++ni)
            bv[s][ni] = *(const bf16x8*)(bb + bo + ni * 512);
    }

    #pragma unroll
    for (int s = 0; s < 16; ++s) {
        const int cur = s % 3;
        if (s + 2 < 16) {
            const int s2  = s + 2;
            const int nxt = s2 % 3;
            const int ao = (s2 >> 1) * 4096 + (s2 & 1) * 2048;
            const int bo = (s2 >> 1) * 32768 + (s2 & 1) * 16384;
            #pragma unroll
            for (int mi = 0; mi < 4; ++mi)
                af[nxt][mi] = *(const bf16x8*)(ab + ao + mi * 512);
            #pragma unroll
            for (int ni = 0; ni < 4; ++ni)
                bv[nxt][ni] = *(const bf16x8*)(bb + bo + ni * 512);
        }
        #pragma unroll
        for (int mi = 0; mi < 4; ++mi)
            #pragma unroll
            for (int ni = 0; ni < 4; ++ni)
                acc[mi][ni] = __builtin_amdgcn_mfma_f32_16x16x32_bf16(
                    af[cur][mi], bv[cur][ni], acc[mi][ni], 0, 0, 0);
    }

    // epilogue: +bias, masked scatter (C/D: col=l15, row=q*4+r)
    int growv[16];
    #pragma unroll
    for (int mi = 0; mi < 4; ++mi)
        #pragma unroll
        for (int r = 0; r < 4; ++r) {
            int rloc = mi * 16 + q * 4 + r;
            growv[mi * 4 + r] = (rloc < m_valid) ? rl[rloc] : -1;
        }
    #pragma unroll
    for (int ni = 0; ni < 4; ++ni) {
        int col = strip * 64 + ni * 16 + l15;
        float bvs = bias[e * NDIM + col];
        #pragma unroll
        for (int mi = 0; mi < 4; ++mi)
            #pragma unroll
            for (int r = 0; r < 4; ++r) {
                int gr = growv[mi * 4 + r];
                if (gr >= 0) out[(size_t)gr * NDIM + col] = acc[mi][ni][r] + bvs;
            }
    }
}

extern "C" void kernel_launch(void* const* d_in, const int* in_sizes, int n_in,
                              void* d_out, int out_size, void* d_ws, size_t ws_size,
                              hipStream_t stream) {
    const float* x      = (const float*)d_in[0];   // (16384, 512) f32
    const int*   groups = (const int*)d_in[1];     // (16384, 2) i32
    const float* W      = (const float*)d_in[2];   // (8, 512, 512) f32
    const float* b      = (const float*)d_in[3];   // (8, 512) f32
    float*       out    = (float*)d_out;           // (16384, 512) f32

    char* ws = (char*)d_ws;
    int*            counts  = (int*)ws;
    int*            ndesc   = (int*)(ws + WS_NDESC_OFF);
    int*            desc    = (int*)(ws + WS_DESC_OFF);
    int*            rowlist = (int*)(ws + WS_ROWLIST_OFF);
    unsigned short* Wf      = (unsigned short*)(ws + WS_WT_OFF);
    unsigned short* xf      = (unsigned short*)(ws + WS_XG_OFF);

    hipMemsetAsync(counts, 0, NEXP * sizeof(int), stream);
    hist_kernel<<<64, 256, 0, stream>>>(groups, counts, rowlist);
    plan_kernel<<<1, 64, 0, stream>>>(counts, ndesc, desc);
    stage_kernel<<<64 + MAX_DESC * 8, 256, 0, stream>>>(x, W, counts, rowlist,
                                                        ndesc, desc, Wf, xf);
    gemm_frag<<<576, 256, 0, stream>>>(xf, counts, rowlist, Wf, b, out,
                                       ndesc, desc);
}